// Round 7
// baseline (294.131 us; speedup 1.0000x reference)
//
#include <hip/hip_runtime.h>

// GRFExactAttention — bf16 MFMA pipeline.
// B=8 N=1024 C=768 H=12 D=64. Inputs/outputs f32; internals bf16 (f32 accum).
// GEMM0/1: 256x256 2-phase double-buffered (T3-minimum). GEMM2: 128x128 m97.
// Attention: LDS-staged double-buffered flash-style (unchanged from R5).

typedef unsigned short u16;
typedef unsigned int u32;
typedef __attribute__((ext_vector_type(8))) short short8;
typedef __attribute__((ext_vector_type(4))) float f32x4;

#define MFMA(a, b, c) __builtin_amdgcn_mfma_f32_16x16x32_bf16((a), (b), (c), 0, 0, 0)

__device__ __forceinline__ u16 f2b(float f) {  // f32 -> bf16 RNE
    unsigned u = __builtin_bit_cast(unsigned, f);
    return (u16)((u + 0x7FFFu + ((u >> 16) & 1u)) >> 16);
}
__device__ __forceinline__ float b2f(u16 h) {
    unsigned u = ((unsigned)h) << 16;
    return __builtin_bit_cast(float, u);
}
// pack 2 f32 -> 1 u32 holding 2 bf16 (lo=a, hi=b), hardware RNE
__device__ __forceinline__ u32 cvt_pk_bf16(float a, float b) {
    u32 r;
    asm("v_cvt_pk_bf16_f32 %0, %1, %2" : "=v"(r) : "v"(a), "v"(b));
    return r;
}
// async global->LDS, 16B per lane; lds dest must be wave-uniform base.
__device__ __forceinline__ void gl_lds16(const u16* g, u16* l) {
    __builtin_amdgcn_global_load_lds(
        (const __attribute__((address_space(1))) u32*)g,
        (__attribute__((address_space(3))) u32*)l, 16, 0, 0);
}

// ---------------------------------------------------------------------------
// elementwise f32 -> bf16
// ---------------------------------------------------------------------------
__global__ __launch_bounds__(256) void k_conv(const float* __restrict__ in,
                                              u16* __restrict__ out, int n) {
    int i = (blockIdx.x * 256 + threadIdx.x) * 4;
    if (i + 3 < n) {
        float4 v = *reinterpret_cast<const float4*>(&in[i]);
        ushort4 o;
        o.x = f2b(v.x); o.y = f2b(v.y); o.z = f2b(v.z); o.w = f2b(v.w);
        *reinterpret_cast<ushort4*>(&out[i]) = o;
    }
}

// ---------------------------------------------------------------------------
// transpose-convert: out[c][r] = bf16(in[r][c]*alpha + (r==c)*delta)
// ---------------------------------------------------------------------------
__global__ __launch_bounds__(256) void k_transconv(const float* __restrict__ in,
                                                   u16* __restrict__ out,
                                                   int R, int Cc, float alpha, float delta) {
    __shared__ float t[32][33];
    const int tx = threadIdx.x & 31, ty = threadIdx.x >> 5;
    const int r0 = blockIdx.y * 32, c0 = blockIdx.x * 32;
#pragma unroll
    for (int k = 0; k < 4; ++k)
        t[ty + 8 * k][tx] = in[(long)(r0 + ty + 8 * k) * Cc + c0 + tx];
    __syncthreads();
#pragma unroll
    for (int k = 0; k < 4; ++k) {
        const int c = c0 + ty + 8 * k, r = r0 + tx;
        float v = t[tx][ty + 8 * k] * alpha + ((r == c) ? delta : 0.f);
        out[(long)c * R + r] = f2b(v);
    }
}

// ---------------------------------------------------------------------------
// bf16 NT GEMM, 256x256 tile, BK=64, 8 waves (2M x 4N), 2-phase dbuf LDS.
// C[M][N] = A[M][K] * B'[N][K]^T.  LDS: 2 x (A 32KB + B 32KB) = 128KB.
// Staging: global_load_lds w16, linear LDS [256][64] (128B rows).
// One vmcnt(0)+barrier per K-tile amortized over 64 MFMAs/wave.
// MODE 0: relu+eps rows<1536, bf16 out. MODE 1: bf16 out, per-z offsets.
// ---------------------------------------------------------------------------
template <int MODE>
__global__ __launch_bounds__(512, 2) void k_gemm256(const u16* __restrict__ A,
                                                    const u16* __restrict__ Bm,
                                                    void* __restrict__ Cv,
                                                    int M, int N, int K,
                                                    int lda, int ldb, int ldc,
                                                    long boffB, long boffC) {
    __shared__ u16 As[2][256 * 64];
    __shared__ u16 Bs[2][256 * 64];
    const int tid = threadIdx.x;
    const int lane = tid & 63, wid = tid >> 6;
    const int lo = lane & 15, hi = lane >> 4;
    const int wr = wid >> 2, wc = wid & 3;  // 2 x 4 wave grid
    const int m0 = blockIdx.y * 256, n0 = blockIdx.x * 256;
    const u16* Bz = Bm + (long)blockIdx.z * boffB;

    // staging: instr i covers LDS rows [i*64 + wid*8, +8); lane l -> row +(l>>3), chunk l&7
    const int srow = wid * 8 + (lane >> 3);
    const int sch = (lane & 7) * 8;
    const u16* Ag = A + (long)(m0 + srow) * lda + sch;
    const u16* Bg = Bz + (long)(n0 + srow) * ldb + sch;
    const int sldsbase = (wid * 8) * 64;

    f32x4 acc[8][4] = {};

    const int NT = K >> 6;
#pragma unroll
    for (int i = 0; i < 4; ++i) {  // prologue: stage tile 0 into buf 0
        gl_lds16(Ag + (long)i * 64 * lda, &As[0][sldsbase + i * 64 * 64]);
        gl_lds16(Bg + (long)i * 64 * ldb, &Bs[0][sldsbase + i * 64 * 64]);
    }
    __syncthreads();

    for (int t = 0; t < NT; ++t) {
        const int cur = t & 1;
        if (t + 1 < NT) {
            const int k1 = (t + 1) << 6;
#pragma unroll
            for (int i = 0; i < 4; ++i) {
                gl_lds16(Ag + (long)i * 64 * lda + k1, &As[cur ^ 1][sldsbase + i * 64 * 64]);
                gl_lds16(Bg + (long)i * 64 * ldb + k1, &Bs[cur ^ 1][sldsbase + i * 64 * 64]);
            }
        }
#pragma unroll
        for (int kk = 0; kk < 2; ++kk) {
            short8 bfr[4];
#pragma unroll
            for (int ni = 0; ni < 4; ++ni)
                bfr[ni] = *reinterpret_cast<const short8*>(
                    &Bs[cur][(wc * 64 + ni * 16 + lo) * 64 + kk * 32 + hi * 8]);
#pragma unroll
            for (int mi = 0; mi < 8; ++mi) {
                const short8 afr = *reinterpret_cast<const short8*>(
                    &As[cur][(wr * 128 + mi * 16 + lo) * 64 + kk * 32 + hi * 8]);
#pragma unroll
                for (int ni = 0; ni < 4; ++ni)
                    acc[mi][ni] = MFMA(afr, bfr[ni], acc[mi][ni]);
            }
        }
        __syncthreads();  // staging(t+1) complete + compute(t) reads done
    }

#pragma unroll
    for (int mi = 0; mi < 8; ++mi)
#pragma unroll
        for (int ni = 0; ni < 4; ++ni)
#pragma unroll
            for (int r = 0; r < 4; ++r) {
                const int m = m0 + wr * 128 + mi * 16 + hi * 4 + r;
                const int n = n0 + wc * 64 + ni * 16 + lo;
                float v = acc[mi][ni][r];
                if (MODE == 0) {
                    if (m < 1536) v = fmaxf(v, 0.f) + 1e-6f;
                    ((u16*)Cv)[(long)m * ldc + n] = f2b(v);
                } else {
                    u16* Cz = (u16*)Cv + (long)blockIdx.z * boffC;
                    Cz[(long)m * ldc + n] = f2b(v);
                }
            }
}

// ---------------------------------------------------------------------------
// bf16 NT GEMM, m97-style 128x128 (for the thin final GEMM), f32 out + bias.
// ---------------------------------------------------------------------------
__global__ __launch_bounds__(256) void k_gemm(const u16* __restrict__ A,
                                              const u16* __restrict__ Bm,
                                              float* __restrict__ Cv,
                                              const float* __restrict__ bias,
                                              int M, int N, int K,
                                              int lda, int ldb, int ldc) {
    __shared__ u16 As[128 * 32];
    __shared__ u16 Bs[128 * 32];
    const int tid = threadIdx.x;
    const int lane = tid & 63, wid = tid >> 6;
    const int lo = lane & 15, hi = lane >> 4;
    const int wr = wid >> 1, wc = wid & 1;
    const int m0 = blockIdx.y * 128, n0 = blockIdx.x * 128;

    const int rA = wid * 32 + (lane >> 2);
    const int ck = (lane & 3) * 8;
    const u16* Ag = A + (long)(m0 + rA) * lda + ck;
    const u16* Bg = Bm + (long)(n0 + rA) * ldb + ck;
    u16* AsW = As + (wid * 32) * 32;
    u16* BsW = Bs + (wid * 32) * 32;

    f32x4 acc[4][4] = {};
    for (int k0 = 0; k0 < K; k0 += 32) {
        __syncthreads();
#pragma unroll
        for (int i = 0; i < 2; ++i) {
            gl_lds16(Ag + (long)i * 16 * lda + k0, AsW + i * 16 * 32);
            gl_lds16(Bg + (long)i * 16 * ldb + k0, BsW + i * 16 * 32);
        }
        __syncthreads();
        short8 af[4], bf_[4];
#pragma unroll
        for (int i = 0; i < 4; ++i)
            af[i] = *reinterpret_cast<const short8*>(&As[(wr * 64 + i * 16 + lo) * 32 + hi * 8]);
#pragma unroll
        for (int j = 0; j < 4; ++j)
            bf_[j] = *reinterpret_cast<const short8*>(&Bs[(wc * 64 + j * 16 + lo) * 32 + hi * 8]);
#pragma unroll
        for (int i = 0; i < 4; ++i)
#pragma unroll
            for (int j = 0; j < 4; ++j)
                acc[i][j] = MFMA(af[i], bf_[j], acc[i][j]);
    }

#pragma unroll
    for (int i = 0; i < 4; ++i)
#pragma unroll
        for (int j = 0; j < 4; ++j)
#pragma unroll
            for (int r = 0; r < 4; ++r) {
                const int m = m0 + wr * 64 + i * 16 + hi * 4 + r;
                const int n = n0 + wc * 64 + j * 16 + lo;
                Cv[(long)m * ldc + n] = acc[i][j][r] + bias[n];
            }
}

// ---------------------------------------------------------------------------
// Fused masked linear attention, LDS-staged + double-buffered (unchanged R5).
// ---------------------------------------------------------------------------
__global__ __launch_bounds__(256) void k_attn2(const u16* __restrict__ qks,
                                               const u16* __restrict__ qkvT,
                                               const u16* __restrict__ mb,
                                               u16* __restrict__ attn) {
    __shared__ u16 Ks[2][64][64];
    __shared__ u16 Vt[2][64][64];
    __shared__ u16 Sb[4][16][72];
    __shared__ float Zs[4][2][16];
    const int tid = threadIdx.x, wid = tid >> 6, lane = tid & 63;
    const int lo = lane & 15, hi = lane >> 4;
    const int n0 = blockIdx.x * 128;
    const int bh = blockIdx.y, b = bh / 12, h = bh % 12;
    const long qbase = (long)b * 1024 * 1536;

    short8 aq[2][2];
#pragma unroll
    for (int qg = 0; qg < 2; ++qg)
#pragma unroll
        for (int kd = 0; kd < 2; ++kd)
            aq[qg][kd] = *reinterpret_cast<const short8*>(
                &qks[qbase + (long)(n0 + wid * 32 + qg * 16 + lo) * 1536 + h * 64 +
                     kd * 32 + hi * 8]);

    const u16* gK[2];
    const u16* gV[2];
    int ldsrow[2];
#pragma unroll
    for (int i = 0; i < 2; ++i) {
        const int r = wid * 16 + i * 8 + (lane >> 3);
        const int cs = (lane & 7) ^ (r & 7);
        ldsrow[i] = wid * 16 + i * 8;
        gK[i] = qks + qbase + (long)r * 1536 + 768 + h * 64 + cs * 8;
        gV[i] = qkvT + (long)(1536 + h * 64 + r) * 8192 + (long)b * 1024 + cs * 8;
    }

    const u16* mrow[2];
#pragma unroll
    for (int qg = 0; qg < 2; ++qg)
        mrow[qg] = mb + (long)(n0 + wid * 32 + qg * 16 + lo) * 1024;

    f32x4 oacc[2][4] = {};
    float rsum[2] = {0.f, 0.f};

#pragma unroll
    for (int i = 0; i < 2; ++i) {
        gl_lds16(gK[i], &Ks[0][ldsrow[i]][0]);
        gl_lds16(gV[i], &Vt[0][ldsrow[i]][0]);
    }
    __syncthreads();

    for (int t = 0; t < 16; ++t) {
        const int cur = t & 1;
        if (t < 15) {
            const long m1 = (long)(t + 1) * 64;
#pragma unroll
            for (int i = 0; i < 2; ++i) {
                gl_lds16(gK[i] + m1 * 1536, &Ks[cur ^ 1][ldsrow[i]][0]);
                gl_lds16(gV[i] + m1, &Vt[cur ^ 1][ldsrow[i]][0]);
            }
        }
        short8 kfr[4][2];
#pragma unroll
        for (int jm = 0; jm < 4; ++jm)
#pragma unroll
            for (int kd = 0; kd < 2; ++kd)
                kfr[jm][kd] = *reinterpret_cast<const short8*>(
                    &Ks[cur][jm * 16 + lo][(((kd * 4 + hi) ^ (lo & 7))) * 8]);

#pragma unroll
        for (int qg = 0; qg < 2; ++qg) {
            f32x4 s[4];
#pragma unroll
            for (int jm = 0; jm < 4; ++jm) {
                f32x4 sj = {};
                sj = MFMA(kfr[jm][0], aq[qg][0], sj);
                sj = MFMA(kfr[jm][1], aq[qg][1], sj);
                s[jm] = sj;
            }
#pragma unroll
            for (int jm = 0; jm < 4; ++jm) {
                ushort4 mv = *reinterpret_cast<const ushort4*>(
                    &mrow[qg][t * 64 + jm * 16 + hi * 4]);
                const float p0 = s[jm][0] * b2f(mv.x);
                const float p1 = s[jm][1] * b2f(mv.y);
                const float p2 = s[jm][2] * b2f(mv.z);
                const float p3 = s[jm][3] * b2f(mv.w);
                rsum[qg] += (p0 + p1) + (p2 + p3);
                uint2 packed;
                packed.x = cvt_pk_bf16(p0, p1);
                packed.y = cvt_pk_bf16(p2, p3);
                *reinterpret_cast<uint2*>(&Sb[wid][lo][jm * 16 + hi * 4]) = packed;
            }
#pragma unroll
            for (int km = 0; km < 2; ++km) {
                const short8 pa =
                    *reinterpret_cast<const short8*>(&Sb[wid][lo][km * 32 + hi * 8]);
#pragma unroll
                for (int jd = 0; jd < 4; ++jd) {
                    const short8 vfr = *reinterpret_cast<const short8*>(
                        &Vt[cur][jd * 16 + lo][(((km * 4 + hi) ^ (lo & 7))) * 8]);
                    oacc[qg][jd] = MFMA(pa, vfr, oacc[qg][jd]);
                }
            }
        }
        __syncthreads();
    }

#pragma unroll
    for (int qg = 0; qg < 2; ++qg) {
        float v = rsum[qg];
        v += __shfl_xor(v, 16);
        v += __shfl_xor(v, 32);
        if (hi == 0) Zs[wid][qg][lo] = 1.f / (v + 1e-6f);
    }
    const long obase = (long)(b * 1024) * 768 + h * 64;
#pragma unroll
    for (int qg = 0; qg < 2; ++qg)
#pragma unroll
        for (int jd = 0; jd < 4; ++jd)
#pragma unroll
            for (int r = 0; r < 4; ++r) {
                const int nr = n0 + wid * 32 + qg * 16 + hi * 4 + r;
                attn[obase + (long)nr * 768 + jd * 16 + lo] =
                    f2b(oacc[qg][jd][r] * Zs[wid][qg][hi * 4 + r]);
            }
}

// ---------------------------------------------------------------------------

extern "C" void kernel_launch(void* const* d_in, const int* in_sizes, int n_in,
                              void* d_out, int out_size, void* d_ws, size_t ws_size,
                              hipStream_t stream) {
    (void)in_sizes; (void)n_in; (void)out_size; (void)ws_size;
    const float* x     = (const float*)d_in[0];
    const float* mask  = (const float*)d_in[1];
    const float* w_qkv = (const float*)d_in[2];
    const float* w_out = (const float*)d_in[3];
    const float* b_out = (const float*)d_in[4];
    float* out = (float*)d_out;

    u16* ws = (u16*)d_ws;  // element (2B) offsets
    u16* xb     = ws;                           // [8192][768]
    u16* wqkvT  = xb + (size_t)8192 * 768;      // [2304][768]
    u16* mTb    = wqkvT + (size_t)2304 * 768;   // [1024][1024]
    u16* woutT  = mTb + (size_t)1024 * 1024;    // [768][768]
    u16* qkvT   = woutT + (size_t)768 * 768;    // [2304][8192]
    u16* qks    = qkvT + (size_t)2304 * 8192;   // [8][1024][1536]
    u16* attnb  = qks + (size_t)8192 * 1536;    // [8192][768]
    u16* mbb    = attnb + (size_t)8192 * 768;   // [1024][1024] bf16 mask

    // conversions / transposes
    k_conv<<<dim3(6144), dim3(256), 0, stream>>>(x, xb, 8192 * 768);
    k_conv<<<dim3(1024), dim3(256), 0, stream>>>(mask, mbb, 1024 * 1024);
    k_transconv<<<dim3(72, 24), dim3(256), 0, stream>>>(w_qkv, wqkvT, 768, 2304, 1.f, 0.f);
    k_transconv<<<dim3(32, 32), dim3(256), 0, stream>>>(mask, mTb, 1024, 1024, 0.1f, 1.f);
    k_transconv<<<dim3(24, 24), dim3(256), 0, stream>>>(w_out, woutT, 768, 768, 1.f, 0.f);

    // qkvT = w_qkvT @ xT (relu+eps on q,k rows)  [2304 x 8192, K=768]
    k_gemm256<0><<<dim3(32, 9, 1), dim3(512), 0, stream>>>(
        wqkvT, xb, qkvT, 2304, 8192, 768, 768, 768, 8192, 0, 0);
    // qks[b] = M' @ [q'|k']  (per batch)  [1024 x 1536, K=1024]
    k_gemm256<1><<<dim3(6, 4, 8), dim3(512), 0, stream>>>(
        mTb, qkvT, qks, 1024, 1536, 1024, 1024, 8192, 1536,
        1024L, 1024L * 1536L);
    // fused attention
    k_attn2<<<dim3(8, 96), dim3(256), 0, stream>>>(qks, qkvT, mbb, attnb);
    // out = attn @ w_out + b_out  [8192 x 768, K=768]
    k_gemm<<<dim3(6, 64, 1), dim3(256), 0, stream>>>(
        attnb, woutT, out, b_out, 8192, 768, 768, 768, 768, 768);
}